// Round 1
// baseline (7624.949 us; speedup 1.0000x reference)
//
#include <hip/hip_runtime.h>
#include <math.h>

// ---------------- problem constants ----------------
// B=4, H=1024, W=1536; Hf=64, Wf=96; C=64; grid 256x256; D=16 depth bins.
// conv chain: (3,1024,1536)->(32,512,768)->(64,256,384)->(128,128,192)->(128,64,96)

// Direct 3x3 conv + folded-BN + ReLU. Requires (OH*OW) % 256 == 0 so that a
// 256-thread block shares one (b, oc) -> weights cached in LDS (broadcast reads).
template<int STRIDE>
__global__ __launch_bounds__(256) void conv3x3_bn(
    const float* __restrict__ in, const float* __restrict__ wgt,
    const float* __restrict__ scl, const float* __restrict__ sft,
    float* __restrict__ out,
    int IC, int IH, int IW, int OC, int OH, int OW) {
  __shared__ float wl[1152];  // up to IC=128 * 9
  int idx = blockIdx.x * 256 + threadIdx.x;
  int ox = idx % OW;
  int tmp = idx / OW;
  int oy = tmp % OH;
  tmp /= OH;
  int oc = tmp % OC;
  int b = tmp / OC;
  int wn = IC * 9;
  for (int i = threadIdx.x; i < wn; i += 256) wl[i] = wgt[oc * wn + i];
  __syncthreads();

  const float* ip0 = in + (b * IC) * IH * IW;
  int iy0 = oy * STRIDE - 1;
  int ix0 = ox * STRIDE - 1;
  int plane = IH * IW;
  float acc = 0.f;
  if (iy0 >= 0 && iy0 + 2 < IH && ix0 >= 0 && ix0 + 2 < IW) {
    const float* ip = ip0 + iy0 * IW + ix0;
    const float* wp = wl;
    for (int ic = 0; ic < IC; ++ic) {
#pragma unroll
      for (int ky = 0; ky < 3; ++ky) {
        const float* r = ip + ky * IW;
        acc += r[0] * wp[ky * 3 + 0];
        acc += r[1] * wp[ky * 3 + 1];
        acc += r[2] * wp[ky * 3 + 2];
      }
      ip += plane;
      wp += 9;
    }
  } else {
    for (int ic = 0; ic < IC; ++ic) {
      const float* ip = ip0 + ic * plane;
      const float* wp = wl + ic * 9;
#pragma unroll
      for (int ky = 0; ky < 3; ++ky) {
        int iy = iy0 + ky;
        if (iy < 0 || iy >= IH) continue;
#pragma unroll
        for (int kx = 0; kx < 3; ++kx) {
          int ix = ix0 + kx;
          if (ix < 0 || ix >= IW) continue;
          acc += ip[iy * IW + ix] * wp[ky * 3 + kx];
        }
      }
    }
  }
  float r = acc * scl[oc] + sft[oc];
  out[idx] = r > 0.f ? r : 0.f;
}

// 1x1 conv 128->64 + bias, output in (B, Hf, Wf, C) layout (channel fastest).
// One thread per (pixel, c); a 64-lane wave covers one pixel -> fh loads are
// wave-uniform (broadcast); weights staged transposed in LDS (stride-1 reads).
__global__ __launch_bounds__(256) void feat_head(
    const float* __restrict__ fh, const float* __restrict__ fw2,
    const float* __restrict__ fb, float* __restrict__ feats) {
  __shared__ float wl[128 * 64];
  for (int i = threadIdx.x; i < 8192; i += 256) {
    int c = i & 63, ic = i >> 6;
    wl[i] = fw2[c * 128 + ic];
  }
  __syncthreads();
  int t = blockIdx.x * 256 + threadIdx.x;  // 24576*64 total
  int c = t & 63;
  int p = t >> 6;
  int b = p / 6144;
  int rem = p % 6144;
  const float* fp = fh + (b * 128) * 6144 + rem;
  float acc = fb[c];
#pragma unroll 4
  for (int ic = 0; ic < 128; ++ic) acc += fp[ic * 6144] * wl[(ic << 6) + c];
  feats[t] = acc;
}

// Depth + opacity heads fused with softmax-expected depth, backprojection to
// lidar frame, voxelization and base-weight computation. One thread per pixel.
__global__ __launch_bounds__(256) void depth_head(
    const float* __restrict__ x4, const float* __restrict__ dw,
    const float* __restrict__ dbias, const float* __restrict__ oww,
    const float* __restrict__ obias, const float* __restrict__ camK,
    const float* __restrict__ Tlc,
    int* __restrict__ xio, int* __restrict__ yio, float* __restrict__ bwo) {
  __shared__ float dwl[16 * 128];
  __shared__ float owl[128];
  for (int i = threadIdx.x; i < 2048; i += 256) dwl[i] = dw[i];
  if (threadIdx.x < 128) owl[threadIdx.x] = oww[threadIdx.x];
  __syncthreads();
  int p = blockIdx.x * 256 + threadIdx.x;  // 24576 pixels
  int b = p / 6144;
  int rem = p % 6144;
  int y = rem / 96;
  int x = rem % 96;

  float lg[16];
#pragma unroll
  for (int j = 0; j < 16; ++j) lg[j] = dbias[j];
  float oa = obias[0];
  const float* fp = x4 + (b * 128) * 6144 + rem;
  for (int ic = 0; ic < 128; ++ic) {
    float f = fp[ic * 6144];
#pragma unroll
    for (int j = 0; j < 16; ++j) lg[j] += f * dwl[j * 128 + ic];
    oa += f * owl[ic];
  }
  float m = lg[0];
#pragma unroll
  for (int j = 1; j < 16; ++j) m = fmaxf(m, lg[j]);
  float se = 0.f, sz = 0.f;
#pragma unroll
  for (int j = 0; j < 16; ++j) {
    float e = expf(lg[j] - m);
    se += e;
    sz += e * (1.0f + (float)j * (59.0f / 15.0f));
  }
  float z = sz / se;
  float op = 1.f / (1.f + expf(-oa));

  const float* K = camK + b * 9;
  float fx = fmaxf(K[0], 1e-6f), fy = fmaxf(K[4], 1e-6f);
  float cx = K[2], cy = K[5];
  float xs = ((float)x + 0.5f) * 16.0f;  // img_w/Wf = 1536/96
  float ys = ((float)y + 0.5f) * 16.0f;  // img_h/Hf = 1024/64
  float xc = (xs - cx) * z / fx;
  float yc = (ys - cy) * z / fy;
  const float* T = Tlc + b * 16;
  float xw = T[0] * xc + T[1] * yc + T[2] * z + T[3];
  float yw = T[4] * xc + T[5] * yc + T[6] * z + T[7];
  float zw = T[8] * xc + T[9] * yc + T[10] * z + T[11];
  float xif = floorf((xw - (-51.2f)) / 0.4f);
  float yif = floorf((yw - (-51.2f)) / 0.4f);
  int xi = (int)xif, yi = (int)yif;
  bool inb = xi >= 0 && xi < 256 && yi >= 0 && yi < 256 && zw >= -5.0f && zw < 3.0f;
  float bw = (op >= 0.05f && inb) ? op : 0.f;
  xio[p] = xi;
  yio[p] = yi;
  bwo[p] = bw;
}

__global__ __launch_bounds__(256) void zerof4(float4* __restrict__ p) {
  int i = blockIdx.x * 256 + threadIdx.x;
  p[i] = make_float4(0.f, 0.f, 0.f, 0.f);
}

// 9-tap Gaussian scatter. One thread per (pixel, channel); lane c==0 also
// accumulates the weight canvas.
__global__ __launch_bounds__(256) void splat(
    const float* __restrict__ feats, const int* __restrict__ xi,
    const int* __restrict__ yi, const float* __restrict__ bw,
    float* __restrict__ canvas, float* __restrict__ wacc) {
  int t = blockIdx.x * 256 + threadIdx.x;
  int c = t & 63;
  int p = t >> 6;
  float w0 = bw[p];
  if (w0 == 0.f) return;
  int X = xi[p], Y = yi[p];
  int b = p / 6144;
  float fv = feats[t];
  float* cb = canvas + (b << 22);  // b*65536*64
  float* wb = wacc + (b << 16);
  const float kwt[3] = {1.0f, 0.45783335f, 0.20961137f};  // exp(-r2/1.28)
#pragma unroll
  for (int dy = -1; dy <= 1; ++dy) {
    int ty = Y + dy;
    if (ty < 0 || ty > 255) continue;
#pragma unroll
    for (int dx = -1; dx <= 1; ++dx) {
      int tx = X + dx;
      if (tx < 0 || tx > 255) continue;
      float kw = kwt[dx * dx + dy * dy];
      atomicAdd(&cb[(((ty << 8) + tx) << 6) + c], fv * w0 * kw);
      if (c == 0) atomicAdd(&wb[(ty << 8) + tx], w0 * kw);
    }
  }
}

// normalize + NHWC->NCHW transpose via LDS tile (64 pixels x 64 channels).
__global__ __launch_bounds__(256) void normalize_out(
    const float* __restrict__ canvas, const float* __restrict__ wacc,
    float* __restrict__ out) {
  __shared__ float tile[64][65];
  int blk = blockIdx.x;     // 4096 = 4 * (65536/64)
  int b = blk >> 10;
  int s0 = (blk & 1023) << 6;
  int tid = threadIdx.x;
  const float* cb = canvas + ((size_t)b << 22);
  const float* wb = wacc + (b << 16);
#pragma unroll
  for (int it = 0; it < 16; ++it) {
    int l = it * 256 + tid;
    int pix = l >> 6, ch = l & 63;
    float w = wb[s0 + pix];
    float n = w > 0.f ? 1.f / fmaxf(w, 1e-6f) : 0.f;
    tile[pix][ch] = cb[(size_t)(s0 + pix) * 64 + ch] * n;
  }
  __syncthreads();
  float* ob = out + ((size_t)b << 22);
#pragma unroll
  for (int it = 0; it < 16; ++it) {
    int l = it * 256 + tid;
    int ch = l >> 6, pix = l & 63;
    ob[(size_t)ch * 65536 + s0 + pix] = tile[pix][ch];
  }
}

extern "C" void kernel_launch(void* const* d_in, const int* in_sizes, int n_in,
                              void* d_out, int out_size, void* d_ws, size_t ws_size,
                              hipStream_t stream) {
  const float* images = (const float*)d_in[0];
  const float* camK   = (const float*)d_in[1];
  const float* Tlc    = (const float*)d_in[2];
  const float* w1 = (const float*)d_in[3];
  const float* s1 = (const float*)d_in[4];
  const float* b1 = (const float*)d_in[5];
  const float* w2 = (const float*)d_in[6];
  const float* s2 = (const float*)d_in[7];
  const float* b2 = (const float*)d_in[8];
  const float* w3 = (const float*)d_in[9];
  const float* s3 = (const float*)d_in[10];
  const float* b3 = (const float*)d_in[11];
  const float* w4 = (const float*)d_in[12];
  const float* s4 = (const float*)d_in[13];
  const float* b4 = (const float*)d_in[14];
  const float* fw1 = (const float*)d_in[15];
  const float* fs1 = (const float*)d_in[16];
  const float* fb1 = (const float*)d_in[17];
  const float* fw2 = (const float*)d_in[18];
  const float* fbias2 = (const float*)d_in[19];
  const float* dw = (const float*)d_in[20];
  const float* dbias = (const float*)d_in[21];
  const float* ow = (const float*)d_in[22];
  const float* obias = (const float*)d_in[23];
  float* out = (float*)d_out;

  // workspace layout (floats), aliased ping-pong:
  //   A [50,331,648]: conv1 out -> conv3 out -> canvas(16.7M)+wacc(262K)
  //   B [25,165,824]: conv2 out -> conv4(3.1M) | fh(3.1M) | feats(1.57M) | xi/yi/bw
  // peak ws = 75,497,472 floats = 302 MB
  float* ws = (float*)d_ws;
  float* A = ws;
  float* Bb = ws + 50331648;
  float* c4  = Bb;                 // conv4 out (B,128,64,96)
  float* fhb = Bb + 3145728;       // fh (B,128,64,96)
  float* ftb = Bb + 6291456;       // features (B,Hf,Wf,64)
  int*   xib = (int*)(Bb + 7864320);
  int*   yib = xib + 24576;
  float* bwb = (float*)(yib + 24576);
  float* canvas = A;               // (B*65536, 64)
  float* waccb  = A + 16777216;    // (B*65536)

  // conv backbone
  conv3x3_bn<2><<<196608, 256, 0, stream>>>(images, w1, s1, b1, A, 3, 1024, 1536, 32, 512, 768);
  conv3x3_bn<2><<<98304, 256, 0, stream>>>(A, w2, s2, b2, Bb, 32, 512, 768, 64, 256, 384);
  conv3x3_bn<2><<<49152, 256, 0, stream>>>(Bb, w3, s3, b3, A, 64, 256, 384, 128, 128, 192);
  conv3x3_bn<2><<<12288, 256, 0, stream>>>(A, w4, s4, b4, c4, 128, 128, 192, 128, 64, 96);
  // feature head
  conv3x3_bn<1><<<12288, 256, 0, stream>>>(c4, fw1, fs1, fb1, fhb, 128, 64, 96, 128, 64, 96);
  feat_head<<<6144, 256, 0, stream>>>(fhb, fw2, fbias2, ftb);
  // depth/opacity + backprojection
  depth_head<<<96, 256, 0, stream>>>(c4, dw, dbias, ow, obias, camK, Tlc, xib, yib, bwb);
  // zero canvas + wacc (17,039,360 floats / 4 per thread / 256 per block)
  zerof4<<<16640, 256, 0, stream>>>((float4*)canvas);
  // splat + normalize/transpose
  splat<<<6144, 256, 0, stream>>>(ftb, xib, yib, bwb, canvas, waccb);
  normalize_out<<<4096, 256, 0, stream>>>(canvas, waccb, out);
}

// Round 5
// 4006.268 us; speedup vs baseline: 1.9033x; 1.9033x over previous
//
#include <hip/hip_runtime.h>
#include <math.h>

// ---------------- problem constants ----------------
// B=4, H=1024, W=1536; Hf=64, Wf=96; C=64; grid 256x256; D=16 depth bins.
// conv chain: (3,1024,1536)->(32,512,768)->(64,256,384)->(128,128,192)->(128,64,96)
//
// R4 post-mortem: absmax bit-identical (0.203125) across R2/R3/R4 although
// conv3/4/fw1 numerics changed between R2 (IC-chunked) and R3/R4 (sequential)
// => error source is in the tiled conv1/conv2 path (identical across R2-R4).
// THIS ROUND BISECTS: conv1+conv2 use the R1-verbatim naive kernel (passing
// numerics), conv3/conv4/fw1 use the tiled kernel. If PASS: bug confirmed in
// tiled conv1/2 config. If FAIL 0.203125: bug in tiled conv3/4/fw1; flip.

// ---------- R1-verbatim naive conv (used for conv1, conv2) ----------
template<int STRIDE>
__global__ __launch_bounds__(256) void conv3x3_bn(
    const float* __restrict__ in, const float* __restrict__ wgt,
    const float* __restrict__ scl, const float* __restrict__ sft,
    float* __restrict__ out,
    int IC, int IH, int IW, int OC, int OH, int OW) {
  __shared__ float wl[1152];  // up to IC=128 * 9
  int idx = blockIdx.x * 256 + threadIdx.x;
  int ox = idx % OW;
  int tmp = idx / OW;
  int oy = tmp % OH;
  tmp /= OH;
  int oc = tmp % OC;
  int b = tmp / OC;
  int wn = IC * 9;
  for (int i = threadIdx.x; i < wn; i += 256) wl[i] = wgt[oc * wn + i];
  __syncthreads();

  const float* ip0 = in + (b * IC) * IH * IW;
  int iy0 = oy * STRIDE - 1;
  int ix0 = ox * STRIDE - 1;
  int plane = IH * IW;
  float acc = 0.f;
  if (iy0 >= 0 && iy0 + 2 < IH && ix0 >= 0 && ix0 + 2 < IW) {
    const float* ip = ip0 + iy0 * IW + ix0;
    const float* wp = wl;
    for (int ic = 0; ic < IC; ++ic) {
#pragma unroll
      for (int ky = 0; ky < 3; ++ky) {
        const float* r = ip + ky * IW;
        acc += r[0] * wp[ky * 3 + 0];
        acc += r[1] * wp[ky * 3 + 1];
        acc += r[2] * wp[ky * 3 + 2];
      }
      ip += plane;
      wp += 9;
    }
  } else {
    for (int ic = 0; ic < IC; ++ic) {
      const float* ip = ip0 + ic * plane;
      const float* wp = wl + ic * 9;
#pragma unroll
      for (int ky = 0; ky < 3; ++ky) {
        int iy = iy0 + ky;
        if (iy < 0 || iy >= IH) continue;
#pragma unroll
        for (int kx = 0; kx < 3; ++kx) {
          int ix = ix0 + kx;
          if (ix < 0 || ix >= IW) continue;
          acc += ip[iy * IW + ix] * wp[ky * 3 + kx];
        }
      }
    }
  }
  float r = acc * scl[oc] + sft[oc];
  out[idx] = r > 0.f ? r : 0.f;
}

// ---------- tiled conv (used for conv3, conv4, fw1) ----------
template<int STRIDE, int IC, int OCB, int OCT, int NOC4, int TY, int TX>
__global__ __launch_bounds__(256) void conv3x3_t(
    const float* __restrict__ in, const float* __restrict__ wgt,
    const float* __restrict__ scl, const float* __restrict__ sft,
    float* __restrict__ out, int IH, int IW, int OH, int OW) {
  constexpr int OCG = NOC4 * 4;          // oc per thread
  constexpr int NOCG = OCB / OCG;        // thread groups along oc
  constexpr int NPIX_T = 256 / NOCG;     // threads along pixel dim
  constexpr int PIX = (TY * TX) / NPIX_T;  // pixels per thread
  constexpr int PH = (TY - 1) * STRIDE + 3;
  constexpr int PW = (TX - 1) * STRIDE + 3;
  __shared__ float patch[PH * PW];
  __shared__ float wl[9 * OCB];          // [k][oc]

  int NTY = OH / TY, NTX = OW / TX;
  int ntiles = 4 * NTY * NTX;
  int ocs = blockIdx.x / ntiles;         // oc-split index
  int r = blockIdx.x % ntiles;
  int b = r / (NTY * NTX);
  int t = r % (NTY * NTX);
  int tyi = t / NTX, txi = t % NTX;
  int oc_base = ocs * OCB;

  int tid = threadIdx.x;
  int pid = tid % NPIX_T;
  int ocg = tid / NPIX_T;

  int off[PIX], pyv[PIX], pxv[PIX];
#pragma unroll
  for (int i = 0; i < PIX; ++i) {
    int p = i * NPIX_T + pid;
    pyv[i] = p / TX;
    pxv[i] = p % TX;
    off[i] = (pyv[i] * STRIDE) * PW + pxv[i] * STRIDE;
  }

  float4 acc[PIX][NOC4];
#pragma unroll
  for (int i = 0; i < PIX; ++i)
#pragma unroll
    for (int j = 0; j < NOC4; ++j) acc[i][j] = make_float4(0.f, 0.f, 0.f, 0.f);

  const size_t plane_in = (size_t)IH * IW;
  const float* ibase = in + (size_t)b * IC * plane_in;
  int iy0 = tyi * TY * STRIDE - 1;
  int ix0 = txi * TX * STRIDE - 1;

#pragma unroll 1
  for (int ic = 0; ic < IC; ++ic) {
    const float* ip = ibase + (size_t)ic * plane_in;
    for (int i = tid; i < PH * PW; i += 256) {
      int py = i / PW, px = i % PW;
      int iy = iy0 + py, ix = ix0 + px;
      float v = 0.f;
      if (iy >= 0 && iy < IH && ix >= 0 && ix < IW) v = ip[(size_t)iy * IW + ix];
      patch[i] = v;
    }
    for (int i = tid; i < 9 * OCB; i += 256) {
      int oc = i / 9, k = i % 9;
      wl[k * OCB + oc] = wgt[((size_t)(oc_base + oc) * IC + ic) * 9 + k];
    }
    __syncthreads();

    const float4* wl4 = (const float4*)wl;
#pragma unroll
    for (int ky = 0; ky < 3; ++ky) {
#pragma unroll
      for (int kx = 0; kx < 3; ++kx) {
        float pv[PIX];
#pragma unroll
        for (int i = 0; i < PIX; ++i) pv[i] = patch[off[i] + ky * PW + kx];
        const float4* wr = wl4 + (ky * 3 + kx) * (OCB / 4) + ocg * NOC4;
#pragma unroll
        for (int j = 0; j < NOC4; ++j) {
          float4 w = wr[j];
#pragma unroll
          for (int i = 0; i < PIX; ++i) {
            acc[i][j].x = __builtin_fmaf(pv[i], w.x, acc[i][j].x);
            acc[i][j].y = __builtin_fmaf(pv[i], w.y, acc[i][j].y);
            acc[i][j].z = __builtin_fmaf(pv[i], w.z, acc[i][j].z);
            acc[i][j].w = __builtin_fmaf(pv[i], w.w, acc[i][j].w);
          }
        }
      }
    }
    __syncthreads();
  }

  int plane = OH * OW;
#pragma unroll
  for (int i = 0; i < PIX; ++i) {
    int oy = tyi * TY + pyv[i];
    int ox = txi * TX + pxv[i];
#pragma unroll
    for (int j = 0; j < NOC4; ++j) {
      int oc0 = oc_base + ocg * OCG + j * 4;
      float4 v = acc[i][j];
      float4 sc = ((const float4*)scl)[oc0 >> 2];
      float4 sh = ((const float4*)sft)[oc0 >> 2];
      float rx = __builtin_fmaf(v.x, sc.x, sh.x);
      float ry = __builtin_fmaf(v.y, sc.y, sh.y);
      float rz = __builtin_fmaf(v.z, sc.z, sh.z);
      float rw = __builtin_fmaf(v.w, sc.w, sh.w);
      rx = rx > 0.f ? rx : 0.f;
      ry = ry > 0.f ? ry : 0.f;
      rz = rz > 0.f ? rz : 0.f;
      rw = rw > 0.f ? rw : 0.f;
      size_t base = ((size_t)b * OCT + oc0) * plane + oy * OW + ox;
      out[base] = rx;
      out[base + plane] = ry;
      out[base + 2 * (size_t)plane] = rz;
      out[base + 3 * (size_t)plane] = rw;
    }
  }
}

// 1x1 conv 128->64 + bias, output in (B, Hf, Wf, C) layout (channel fastest).
__global__ __launch_bounds__(256) void feat_head(
    const float* __restrict__ fh, const float* __restrict__ fw2,
    const float* __restrict__ fb, float* __restrict__ feats) {
  __shared__ float wl[128 * 64];
  for (int i = threadIdx.x; i < 8192; i += 256) {
    int c = i & 63, ic = i >> 6;
    wl[i] = fw2[c * 128 + ic];
  }
  __syncthreads();
  int t = blockIdx.x * 256 + threadIdx.x;  // 24576*64 total
  int c = t & 63;
  int p = t >> 6;
  int b = p / 6144;
  int rem = p % 6144;
  const float* fp = fh + (b * 128) * 6144 + rem;
  float acc = fb[c];
#pragma unroll 4
  for (int ic = 0; ic < 128; ++ic) acc += fp[ic * 6144] * wl[(ic << 6) + c];
  feats[t] = acc;
}

// Depth + opacity heads fused with softmax-expected depth, backprojection,
// voxelization, base-weight. One thread per pixel. (R1-verbatim)
__global__ __launch_bounds__(256) void depth_head(
    const float* __restrict__ x4, const float* __restrict__ dw,
    const float* __restrict__ dbias, const float* __restrict__ oww,
    const float* __restrict__ obias, const float* __restrict__ camK,
    const float* __restrict__ Tlc,
    int* __restrict__ xio, int* __restrict__ yio, float* __restrict__ bwo) {
  __shared__ float dwl[16 * 128];
  __shared__ float owl[128];
  for (int i = threadIdx.x; i < 2048; i += 256) dwl[i] = dw[i];
  if (threadIdx.x < 128) owl[threadIdx.x] = oww[threadIdx.x];
  __syncthreads();
  int p = blockIdx.x * 256 + threadIdx.x;  // 24576 pixels
  int b = p / 6144;
  int rem = p % 6144;
  int y = rem / 96;
  int x = rem % 96;

  float lg[16];
#pragma unroll
  for (int j = 0; j < 16; ++j) lg[j] = dbias[j];
  float oa = obias[0];
  const float* fp = x4 + (b * 128) * 6144 + rem;
  for (int ic = 0; ic < 128; ++ic) {
    float f = fp[ic * 6144];
#pragma unroll
    for (int j = 0; j < 16; ++j) lg[j] += f * dwl[j * 128 + ic];
    oa += f * owl[ic];
  }
  float m = lg[0];
#pragma unroll
  for (int j = 1; j < 16; ++j) m = fmaxf(m, lg[j]);
  float se = 0.f, sz = 0.f;
#pragma unroll
  for (int j = 0; j < 16; ++j) {
    float e = expf(lg[j] - m);
    se += e;
    sz += e * (1.0f + (float)j * (59.0f / 15.0f));
  }
  float z = sz / se;
  float op = 1.f / (1.f + expf(-oa));

  const float* K = camK + b * 9;
  float fx = fmaxf(K[0], 1e-6f), fy = fmaxf(K[4], 1e-6f);
  float cx = K[2], cy = K[5];
  float xs = ((float)x + 0.5f) * 16.0f;  // img_w/Wf = 1536/96
  float ys = ((float)y + 0.5f) * 16.0f;  // img_h/Hf = 1024/64
  float xc = (xs - cx) * z / fx;
  float yc = (ys - cy) * z / fy;
  const float* T = Tlc + b * 16;
  float xw = T[0] * xc + T[1] * yc + T[2] * z + T[3];
  float yw = T[4] * xc + T[5] * yc + T[6] * z + T[7];
  float zw = T[8] * xc + T[9] * yc + T[10] * z + T[11];
  float xif = floorf((xw - (-51.2f)) / 0.4f);
  float yif = floorf((yw - (-51.2f)) / 0.4f);
  int xi = (int)xif, yi = (int)yif;
  bool inb = xi >= 0 && xi < 256 && yi >= 0 && yi < 256 && zw >= -5.0f && zw < 3.0f;
  float bw = (op >= 0.05f && inb) ? op : 0.f;
  xio[p] = xi;
  yio[p] = yi;
  bwo[p] = bw;
}

__global__ __launch_bounds__(256) void zerof4(float4* __restrict__ p) {
  int i = blockIdx.x * 256 + threadIdx.x;
  p[i] = make_float4(0.f, 0.f, 0.f, 0.f);
}

// 9-tap Gaussian scatter. One thread per (pixel, channel). (R1-verbatim)
__global__ __launch_bounds__(256) void splat(
    const float* __restrict__ feats, const int* __restrict__ xi,
    const int* __restrict__ yi, const float* __restrict__ bw,
    float* __restrict__ canvas, float* __restrict__ wacc) {
  int t = blockIdx.x * 256 + threadIdx.x;
  int c = t & 63;
  int p = t >> 6;
  float w0 = bw[p];
  if (w0 == 0.f) return;
  int X = xi[p], Y = yi[p];
  int b = p / 6144;
  float fv = feats[t];
  float* cb = canvas + ((size_t)b << 22);
  float* wb = wacc + (b << 16);
  const float kwt[3] = {1.0f, 0.45783335f, 0.20961137f};  // exp(-r2/1.28)
#pragma unroll
  for (int dy = -1; dy <= 1; ++dy) {
    int ty = Y + dy;
    if (ty < 0 || ty > 255) continue;
#pragma unroll
    for (int dx = -1; dx <= 1; ++dx) {
      int tx = X + dx;
      if (tx < 0 || tx > 255) continue;
      float kw = kwt[dx * dx + dy * dy];
      atomicAdd(&cb[(((ty << 8) + tx) << 6) + c], fv * w0 * kw);
      if (c == 0) atomicAdd(&wb[(ty << 8) + tx], w0 * kw);
    }
  }
}

// normalize + NHWC->NCHW transpose via LDS tile. (R1-verbatim)
__global__ __launch_bounds__(256) void normalize_out(
    const float* __restrict__ canvas, const float* __restrict__ wacc,
    float* __restrict__ out) {
  __shared__ float tile[64][65];
  int blk = blockIdx.x;  // 4096 = 4 * 1024
  int b = blk >> 10;
  int s0 = (blk & 1023) << 6;
  int tid = threadIdx.x;
  const float* cb = canvas + ((size_t)b << 22);
  const float* wb = wacc + (b << 16);
#pragma unroll
  for (int it = 0; it < 16; ++it) {
    int l = it * 256 + tid;
    int pix = l >> 6, ch = l & 63;
    float w = wb[s0 + pix];
    float n = w > 0.f ? 1.f / fmaxf(w, 1e-6f) : 0.f;
    tile[pix][ch] = cb[(size_t)(s0 + pix) * 64 + ch] * n;
  }
  __syncthreads();
  float* ob = out + ((size_t)b << 22);
#pragma unroll
  for (int it = 0; it < 16; ++it) {
    int l = it * 256 + tid;
    int ch = l >> 6, pix = l & 63;
    ob[(size_t)ch * 65536 + s0 + pix] = tile[pix][ch];
  }
}

extern "C" void kernel_launch(void* const* d_in, const int* in_sizes, int n_in,
                              void* d_out, int out_size, void* d_ws, size_t ws_size,
                              hipStream_t stream) {
  const float* images = (const float*)d_in[0];
  const float* camK   = (const float*)d_in[1];
  const float* Tlc    = (const float*)d_in[2];
  const float* w1 = (const float*)d_in[3];
  const float* s1 = (const float*)d_in[4];
  const float* b1 = (const float*)d_in[5];
  const float* w2 = (const float*)d_in[6];
  const float* s2 = (const float*)d_in[7];
  const float* b2 = (const float*)d_in[8];
  const float* w3 = (const float*)d_in[9];
  const float* s3 = (const float*)d_in[10];
  const float* b3 = (const float*)d_in[11];
  const float* w4 = (const float*)d_in[12];
  const float* s4 = (const float*)d_in[13];
  const float* b4 = (const float*)d_in[14];
  const float* fw1 = (const float*)d_in[15];
  const float* fs1 = (const float*)d_in[16];
  const float* fb1 = (const float*)d_in[17];
  const float* fw2 = (const float*)d_in[18];
  const float* fbias2 = (const float*)d_in[19];
  const float* dw = (const float*)d_in[20];
  const float* dbias = (const float*)d_in[21];
  const float* ow = (const float*)d_in[22];
  const float* obias = (const float*)d_in[23];
  float* out = (float*)d_out;

  // workspace layout (floats), aliased (same as R1):
  //   A [50,331,648]: conv1 out -> conv3 out (12.58M) -> canvas(16.78M)+wacc(0.26M)
  //   B [25,165,824]: conv2 out -> c4(3.15M) | fh(3.15M) | feats(1.57M) | xi/yi/bw
  float* ws = (float*)d_ws;
  float* A = ws;
  float* Bb = ws + 50331648;
  float* c4   = Bb;                // (B,128,64,96)
  float* fhb  = Bb + 3145728;
  float* ftb  = Bb + 6291456;      // (B,Hf,Wf,64)
  int*   xib  = (int*)(Bb + 7864320);
  int*   yib  = xib + 24576;
  float* bwb  = (float*)(yib + 24576);
  float* canvas = A;
  float* waccb  = A + 16777216;

  // conv1, conv2: R1-verbatim naive (known-good numerics)
  conv3x3_bn<2><<<196608, 256, 0, stream>>>(images, w1, s1, b1, A, 3, 1024, 1536, 32, 512, 768);
  conv3x3_bn<2><<<98304, 256, 0, stream>>>(A, w2, s2, b2, Bb, 32, 512, 768, 64, 256, 384);
  // conv3, conv4, fw1: tiled
  conv3x3_t<2, 64, 64, 128, 8, 8, 32><<<768, 256, 0, stream>>>(
      Bb, w3, s3, b3, A, 256, 384, 128, 192);
  conv3x3_t<2, 128, 32, 128, 4, 8, 16><<<768, 256, 0, stream>>>(
      A, w4, s4, b4, c4, 128, 192, 64, 96);
  conv3x3_t<1, 128, 32, 128, 4, 8, 16><<<768, 256, 0, stream>>>(
      c4, fw1, fs1, fb1, fhb, 64, 96, 64, 96);
  feat_head<<<6144, 256, 0, stream>>>(fhb, fw2, fbias2, ftb);
  depth_head<<<96, 256, 0, stream>>>(c4, dw, dbias, ow, obias, camK, Tlc, xib, yib, bwb);
  zerof4<<<16640, 256, 0, stream>>>((float4*)canvas);
  splat<<<6144, 256, 0, stream>>>(ftb, xib, yib, bwb, canvas, waccb);
  normalize_out<<<4096, 256, 0, stream>>>(canvas, waccb, out);
}

// Round 6
// 3305.799 us; speedup vs baseline: 2.3065x; 1.2119x over previous
//
#include <hip/hip_runtime.h>
#include <math.h>

// ---------------- problem constants ----------------
// B=4, H=1024, W=1536; Hf=64, Wf=96; C=64; grid 256x256; D=16 depth bins.
// conv chain: (3,1024,1536)->(32,512,768)->(64,256,384)->(128,128,192)->(128,64,96)
//
// NUMERICS CONTRACT (R2-R5 post-mortems): conv1/conv2 must keep the R1 naive
// kernel's per-thread fp instruction stream BIT-IDENTICAL — any rounding
// re-roll flips a knife-edge voxel/opacity decision downstream (0.203125
// failure in R2/R3/R4; bisect R5 localized it to the conv1/conv2 path).
// This round changes ONLY the blockIdx->chunk mapping (launch order), which
// cannot change per-output numerics, to fix the 46x HBM over-fetch:
// old chunk order (b, oc, spatial) re-fetches the input plane per oc;
// new order (b, spatial, oc) keeps all-oc blocks for one spatial slab
// concurrent -> input slab stays hot in L2 (conv2 hot set ~4 MB).

// ---------- R1-verbatim naive conv body, remapped launch order ----------
template<int STRIDE>
__global__ __launch_bounds__(256) void conv3x3_bn(
    const float* __restrict__ in, const float* __restrict__ wgt,
    const float* __restrict__ scl, const float* __restrict__ sft,
    float* __restrict__ out,
    int IC, int IH, int IW, int OC, int OH, int OW) {
  __shared__ float wl[1152];  // up to IC=128 * 9
  // --- launch-order remap (pure permutation of 256-output chunks) ---
  int chw = (OH * OW) >> 8;        // chunks per (b,oc) plane; OH*OW % 256 == 0
  int per_b = OC * chw;
  int bb = blockIdx.x / per_b;
  int rem = blockIdx.x % per_b;
  int s = rem / OC;                // spatial chunk (slab) index
  int oc_r = rem % OC;             // oc fastest among concurrent blocks
  int chunk = bb * per_b + oc_r * chw + s;
  int idx = chunk * 256 + threadIdx.x;
  // --- body identical to R1 naive kernel from here on ---
  int ox = idx % OW;
  int tmp = idx / OW;
  int oy = tmp % OH;
  tmp /= OH;
  int oc = tmp % OC;
  int b = tmp / OC;
  int wn = IC * 9;
  for (int i = threadIdx.x; i < wn; i += 256) wl[i] = wgt[oc * wn + i];
  __syncthreads();

  const float* ip0 = in + (b * IC) * IH * IW;
  int iy0 = oy * STRIDE - 1;
  int ix0 = ox * STRIDE - 1;
  int plane = IH * IW;
  float acc = 0.f;
  if (iy0 >= 0 && iy0 + 2 < IH && ix0 >= 0 && ix0 + 2 < IW) {
    const float* ip = ip0 + iy0 * IW + ix0;
    const float* wp = wl;
    for (int ic = 0; ic < IC; ++ic) {
#pragma unroll
      for (int ky = 0; ky < 3; ++ky) {
        const float* r = ip + ky * IW;
        acc += r[0] * wp[ky * 3 + 0];
        acc += r[1] * wp[ky * 3 + 1];
        acc += r[2] * wp[ky * 3 + 2];
      }
      ip += plane;
      wp += 9;
    }
  } else {
    for (int ic = 0; ic < IC; ++ic) {
      const float* ip = ip0 + ic * plane;
      const float* wp = wl + ic * 9;
#pragma unroll
      for (int ky = 0; ky < 3; ++ky) {
        int iy = iy0 + ky;
        if (iy < 0 || iy >= IH) continue;
#pragma unroll
        for (int kx = 0; kx < 3; ++kx) {
          int ix = ix0 + kx;
          if (ix < 0 || ix >= IW) continue;
          acc += ip[iy * IW + ix] * wp[ky * 3 + kx];
        }
      }
    }
  }
  float r = acc * scl[oc] + sft[oc];
  out[idx] = r > 0.f ? r : 0.f;
}

// ---------- tiled conv (used for conv3, conv4, fw1 — R5-verified) ----------
template<int STRIDE, int IC, int OCB, int OCT, int NOC4, int TY, int TX>
__global__ __launch_bounds__(256) void conv3x3_t(
    const float* __restrict__ in, const float* __restrict__ wgt,
    const float* __restrict__ scl, const float* __restrict__ sft,
    float* __restrict__ out, int IH, int IW, int OH, int OW) {
  constexpr int OCG = NOC4 * 4;          // oc per thread
  constexpr int NOCG = OCB / OCG;        // thread groups along oc
  constexpr int NPIX_T = 256 / NOCG;     // threads along pixel dim
  constexpr int PIX = (TY * TX) / NPIX_T;  // pixels per thread
  constexpr int PH = (TY - 1) * STRIDE + 3;
  constexpr int PW = (TX - 1) * STRIDE + 3;
  __shared__ float patch[PH * PW];
  __shared__ float wl[9 * OCB];          // [k][oc]

  int NTY = OH / TY, NTX = OW / TX;
  int ntiles = 4 * NTY * NTX;
  int ocs = blockIdx.x / ntiles;         // oc-split index
  int r = blockIdx.x % ntiles;
  int b = r / (NTY * NTX);
  int t = r % (NTY * NTX);
  int tyi = t / NTX, txi = t % NTX;
  int oc_base = ocs * OCB;

  int tid = threadIdx.x;
  int pid = tid % NPIX_T;
  int ocg = tid / NPIX_T;

  int off[PIX], pyv[PIX], pxv[PIX];
#pragma unroll
  for (int i = 0; i < PIX; ++i) {
    int p = i * NPIX_T + pid;
    pyv[i] = p / TX;
    pxv[i] = p % TX;
    off[i] = (pyv[i] * STRIDE) * PW + pxv[i] * STRIDE;
  }

  float4 acc[PIX][NOC4];
#pragma unroll
  for (int i = 0; i < PIX; ++i)
#pragma unroll
    for (int j = 0; j < NOC4; ++j) acc[i][j] = make_float4(0.f, 0.f, 0.f, 0.f);

  const size_t plane_in = (size_t)IH * IW;
  const float* ibase = in + (size_t)b * IC * plane_in;
  int iy0 = tyi * TY * STRIDE - 1;
  int ix0 = txi * TX * STRIDE - 1;

#pragma unroll 1
  for (int ic = 0; ic < IC; ++ic) {
    const float* ip = ibase + (size_t)ic * plane_in;
    for (int i = tid; i < PH * PW; i += 256) {
      int py = i / PW, px = i % PW;
      int iy = iy0 + py, ix = ix0 + px;
      float v = 0.f;
      if (iy >= 0 && iy < IH && ix >= 0 && ix < IW) v = ip[(size_t)iy * IW + ix];
      patch[i] = v;
    }
    for (int i = tid; i < 9 * OCB; i += 256) {
      int oc = i / 9, k = i % 9;
      wl[k * OCB + oc] = wgt[((size_t)(oc_base + oc) * IC + ic) * 9 + k];
    }
    __syncthreads();

    const float4* wl4 = (const float4*)wl;
#pragma unroll
    for (int ky = 0; ky < 3; ++ky) {
#pragma unroll
      for (int kx = 0; kx < 3; ++kx) {
        float pv[PIX];
#pragma unroll
        for (int i = 0; i < PIX; ++i) pv[i] = patch[off[i] + ky * PW + kx];
        const float4* wr = wl4 + (ky * 3 + kx) * (OCB / 4) + ocg * NOC4;
#pragma unroll
        for (int j = 0; j < NOC4; ++j) {
          float4 w = wr[j];
#pragma unroll
          for (int i = 0; i < PIX; ++i) {
            acc[i][j].x = __builtin_fmaf(pv[i], w.x, acc[i][j].x);
            acc[i][j].y = __builtin_fmaf(pv[i], w.y, acc[i][j].y);
            acc[i][j].z = __builtin_fmaf(pv[i], w.z, acc[i][j].z);
            acc[i][j].w = __builtin_fmaf(pv[i], w.w, acc[i][j].w);
          }
        }
      }
    }
    __syncthreads();
  }

  int plane = OH * OW;
#pragma unroll
  for (int i = 0; i < PIX; ++i) {
    int oy = tyi * TY + pyv[i];
    int ox = txi * TX + pxv[i];
#pragma unroll
    for (int j = 0; j < NOC4; ++j) {
      int oc0 = oc_base + ocg * OCG + j * 4;
      float4 v = acc[i][j];
      float4 sc = ((const float4*)scl)[oc0 >> 2];
      float4 sh = ((const float4*)sft)[oc0 >> 2];
      float rx = __builtin_fmaf(v.x, sc.x, sh.x);
      float ry = __builtin_fmaf(v.y, sc.y, sh.y);
      float rz = __builtin_fmaf(v.z, sc.z, sh.z);
      float rw = __builtin_fmaf(v.w, sc.w, sh.w);
      rx = rx > 0.f ? rx : 0.f;
      ry = ry > 0.f ? ry : 0.f;
      rz = rz > 0.f ? rz : 0.f;
      rw = rw > 0.f ? rw : 0.f;
      size_t base = ((size_t)b * OCT + oc0) * plane + oy * OW + ox;
      out[base] = rx;
      out[base + plane] = ry;
      out[base + 2 * (size_t)plane] = rz;
      out[base + 3 * (size_t)plane] = rw;
    }
  }
}

// 1x1 conv 128->64 + bias, output in (B, Hf, Wf, C) layout (channel fastest).
__global__ __launch_bounds__(256) void feat_head(
    const float* __restrict__ fh, const float* __restrict__ fw2,
    const float* __restrict__ fb, float* __restrict__ feats) {
  __shared__ float wl[128 * 64];
  for (int i = threadIdx.x; i < 8192; i += 256) {
    int c = i & 63, ic = i >> 6;
    wl[i] = fw2[c * 128 + ic];
  }
  __syncthreads();
  int t = blockIdx.x * 256 + threadIdx.x;  // 24576*64 total
  int c = t & 63;
  int p = t >> 6;
  int b = p / 6144;
  int rem = p % 6144;
  const float* fp = fh + (b * 128) * 6144 + rem;
  float acc = fb[c];
#pragma unroll 4
  for (int ic = 0; ic < 128; ++ic) acc += fp[ic * 6144] * wl[(ic << 6) + c];
  feats[t] = acc;
}

// Depth + opacity heads fused with softmax-expected depth, backprojection,
// voxelization, base-weight. One thread per pixel. (R1-verbatim)
__global__ __launch_bounds__(256) void depth_head(
    const float* __restrict__ x4, const float* __restrict__ dw,
    const float* __restrict__ dbias, const float* __restrict__ oww,
    const float* __restrict__ obias, const float* __restrict__ camK,
    const float* __restrict__ Tlc,
    int* __restrict__ xio, int* __restrict__ yio, float* __restrict__ bwo) {
  __shared__ float dwl[16 * 128];
  __shared__ float owl[128];
  for (int i = threadIdx.x; i < 2048; i += 256) dwl[i] = dw[i];
  if (threadIdx.x < 128) owl[threadIdx.x] = oww[threadIdx.x];
  __syncthreads();
  int p = blockIdx.x * 256 + threadIdx.x;  // 24576 pixels
  int b = p / 6144;
  int rem = p % 6144;
  int y = rem / 96;
  int x = rem % 96;

  float lg[16];
#pragma unroll
  for (int j = 0; j < 16; ++j) lg[j] = dbias[j];
  float oa = obias[0];
  const float* fp = x4 + (b * 128) * 6144 + rem;
  for (int ic = 0; ic < 128; ++ic) {
    float f = fp[ic * 6144];
#pragma unroll
    for (int j = 0; j < 16; ++j) lg[j] += f * dwl[j * 128 + ic];
    oa += f * owl[ic];
  }
  float m = lg[0];
#pragma unroll
  for (int j = 1; j < 16; ++j) m = fmaxf(m, lg[j]);
  float se = 0.f, sz = 0.f;
#pragma unroll
  for (int j = 0; j < 16; ++j) {
    float e = expf(lg[j] - m);
    se += e;
    sz += e * (1.0f + (float)j * (59.0f / 15.0f));
  }
  float z = sz / se;
  float op = 1.f / (1.f + expf(-oa));

  const float* K = camK + b * 9;
  float fx = fmaxf(K[0], 1e-6f), fy = fmaxf(K[4], 1e-6f);
  float cx = K[2], cy = K[5];
  float xs = ((float)x + 0.5f) * 16.0f;  // img_w/Wf = 1536/96
  float ys = ((float)y + 0.5f) * 16.0f;  // img_h/Hf = 1024/64
  float xc = (xs - cx) * z / fx;
  float yc = (ys - cy) * z / fy;
  const float* T = Tlc + b * 16;
  float xw = T[0] * xc + T[1] * yc + T[2] * z + T[3];
  float yw = T[4] * xc + T[5] * yc + T[6] * z + T[7];
  float zw = T[8] * xc + T[9] * yc + T[10] * z + T[11];
  float xif = floorf((xw - (-51.2f)) / 0.4f);
  float yif = floorf((yw - (-51.2f)) / 0.4f);
  int xi = (int)xif, yi = (int)yif;
  bool inb = xi >= 0 && xi < 256 && yi >= 0 && yi < 256 && zw >= -5.0f && zw < 3.0f;
  float bw = (op >= 0.05f && inb) ? op : 0.f;
  xio[p] = xi;
  yio[p] = yi;
  bwo[p] = bw;
}

__global__ __launch_bounds__(256) void zerof4(float4* __restrict__ p) {
  int i = blockIdx.x * 256 + threadIdx.x;
  p[i] = make_float4(0.f, 0.f, 0.f, 0.f);
}

// 9-tap Gaussian scatter. One thread per (pixel, channel). (R1-verbatim)
__global__ __launch_bounds__(256) void splat(
    const float* __restrict__ feats, const int* __restrict__ xi,
    const int* __restrict__ yi, const float* __restrict__ bw,
    float* __restrict__ canvas, float* __restrict__ wacc) {
  int t = blockIdx.x * 256 + threadIdx.x;
  int c = t & 63;
  int p = t >> 6;
  float w0 = bw[p];
  if (w0 == 0.f) return;
  int X = xi[p], Y = yi[p];
  int b = p / 6144;
  float fv = feats[t];
  float* cb = canvas + ((size_t)b << 22);
  float* wb = wacc + (b << 16);
  const float kwt[3] = {1.0f, 0.45783335f, 0.20961137f};  // exp(-r2/1.28)
#pragma unroll
  for (int dy = -1; dy <= 1; ++dy) {
    int ty = Y + dy;
    if (ty < 0 || ty > 255) continue;
#pragma unroll
    for (int dx = -1; dx <= 1; ++dx) {
      int tx = X + dx;
      if (tx < 0 || tx > 255) continue;
      float kw = kwt[dx * dx + dy * dy];
      atomicAdd(&cb[(((ty << 8) + tx) << 6) + c], fv * w0 * kw);
      if (c == 0) atomicAdd(&wb[(ty << 8) + tx], w0 * kw);
    }
  }
}

// normalize + NHWC->NCHW transpose via LDS tile. (R1-verbatim)
__global__ __launch_bounds__(256) void normalize_out(
    const float* __restrict__ canvas, const float* __restrict__ wacc,
    float* __restrict__ out) {
  __shared__ float tile[64][65];
  int blk = blockIdx.x;  // 4096 = 4 * 1024
  int b = blk >> 10;
  int s0 = (blk & 1023) << 6;
  int tid = threadIdx.x;
  const float* cb = canvas + ((size_t)b << 22);
  const float* wb = wacc + (b << 16);
#pragma unroll
  for (int it = 0; it < 16; ++it) {
    int l = it * 256 + tid;
    int pix = l >> 6, ch = l & 63;
    float w = wb[s0 + pix];
    float n = w > 0.f ? 1.f / fmaxf(w, 1e-6f) : 0.f;
    tile[pix][ch] = cb[(size_t)(s0 + pix) * 64 + ch] * n;
  }
  __syncthreads();
  float* ob = out + ((size_t)b << 22);
#pragma unroll
  for (int it = 0; it < 16; ++it) {
    int l = it * 256 + tid;
    int ch = l >> 6, pix = l & 63;
    ob[(size_t)ch * 65536 + s0 + pix] = tile[pix][ch];
  }
}

extern "C" void kernel_launch(void* const* d_in, const int* in_sizes, int n_in,
                              void* d_out, int out_size, void* d_ws, size_t ws_size,
                              hipStream_t stream) {
  const float* images = (const float*)d_in[0];
  const float* camK   = (const float*)d_in[1];
  const float* Tlc    = (const float*)d_in[2];
  const float* w1 = (const float*)d_in[3];
  const float* s1 = (const float*)d_in[4];
  const float* b1 = (const float*)d_in[5];
  const float* w2 = (const float*)d_in[6];
  const float* s2 = (const float*)d_in[7];
  const float* b2 = (const float*)d_in[8];
  const float* w3 = (const float*)d_in[9];
  const float* s3 = (const float*)d_in[10];
  const float* b3 = (const float*)d_in[11];
  const float* w4 = (const float*)d_in[12];
  const float* s4 = (const float*)d_in[13];
  const float* b4 = (const float*)d_in[14];
  const float* fw1 = (const float*)d_in[15];
  const float* fs1 = (const float*)d_in[16];
  const float* fb1 = (const float*)d_in[17];
  const float* fw2 = (const float*)d_in[18];
  const float* fbias2 = (const float*)d_in[19];
  const float* dw = (const float*)d_in[20];
  const float* dbias = (const float*)d_in[21];
  const float* ow = (const float*)d_in[22];
  const float* obias = (const float*)d_in[23];
  float* out = (float*)d_out;

  // workspace layout (floats), aliased (same as R1/R5):
  //   A [50,331,648]: conv1 out -> conv3 out (12.58M) -> canvas(16.78M)+wacc(0.26M)
  //   B [25,165,824]: conv2 out -> c4(3.15M) | fh(3.15M) | feats(1.57M) | xi/yi/bw
  float* ws = (float*)d_ws;
  float* A = ws;
  float* Bb = ws + 50331648;
  float* c4   = Bb;                // (B,128,64,96)
  float* fhb  = Bb + 3145728;
  float* ftb  = Bb + 6291456;      // (B,Hf,Wf,64)
  int*   xib  = (int*)(Bb + 7864320);
  int*   yib  = xib + 24576;
  float* bwb  = (float*)(yib + 24576);
  float* canvas = A;
  float* waccb  = A + 16777216;

  // conv1, conv2: naive body (bit-exact) with cache-friendly launch remap
  conv3x3_bn<2><<<196608, 256, 0, stream>>>(images, w1, s1, b1, A, 3, 1024, 1536, 32, 512, 768);
  conv3x3_bn<2><<<98304, 256, 0, stream>>>(A, w2, s2, b2, Bb, 32, 512, 768, 64, 256, 384);
  // conv3, conv4, fw1: tiled (R5-verified)
  conv3x3_t<2, 64, 64, 128, 8, 8, 32><<<768, 256, 0, stream>>>(
      Bb, w3, s3, b3, A, 256, 384, 128, 192);
  conv3x3_t<2, 128, 32, 128, 4, 8, 16><<<768, 256, 0, stream>>>(
      A, w4, s4, b4, c4, 128, 192, 64, 96);
  conv3x3_t<1, 128, 32, 128, 4, 8, 16><<<768, 256, 0, stream>>>(
      c4, fw1, fs1, fb1, fhb, 64, 96, 64, 96);
  feat_head<<<6144, 256, 0, stream>>>(fhb, fw2, fbias2, ftb);
  depth_head<<<96, 256, 0, stream>>>(c4, dw, dbias, ow, obias, camK, Tlc, xib, yib, bwb);
  zerof4<<<16640, 256, 0, stream>>>((float4*)canvas);
  splat<<<6144, 256, 0, stream>>>(ftb, xib, yib, bwb, canvas, waccb);
  normalize_out<<<4096, 256, 0, stream>>>(canvas, waccb, out);
}

// Round 9
// 3102.828 us; speedup vs baseline: 2.4574x; 1.0654x over previous
//
#include <hip/hip_runtime.h>
#include <math.h>

// ---------------- problem constants ----------------
// B=4, H=1024, W=1536; Hf=64, Wf=96; C=64; grid 256x256; D=16 depth bins.
// conv chain: (3,1024,1536)->(32,512,768)->(64,256,384)->(128,128,192)->(128,64,96)
//
// NUMERICS LEDGER (final model):
//  R1 naive conv1/conv2: PASS 0.015625. Every restructured conv1/conv2
//  (R2/R3/R4 tiled, R7 tiled-A/B, R8 moc — at least two index-verified) FAILS
//  at exactly 0.203125. Model: fast-math reassociation gives the naive loop a
//  compiler-chosen multi-accumulator realization; strict fmaf chains are a
//  different realization; knife-edge point p* flips between them and its
//  splat-delta is the constant 0.203125. conv3/4/fw1 tiled (fmaf) PASS (R5):
//  their perturbation of z is below p*'s margin (fewer amplification layers).
//  => conv1/conv2 BODIES ARE LOCKED (R1 source). Only launch-order
//  permutations are allowed (R6 precedent: prologue remap edit passed).
//  THIS ROUND: XCD-banded remap. blockIdx&7 -> XCD (round-robin dispatch);
//  each XCD gets disjoint 16-output-row bands (conv2 hot set 3.2MB, conv1
//  0.6MB -- fits per-XCD 4MiB L2), killing the 4.2x cross-XCD re-fetch.

// ---------- R1-verbatim naive conv body; XCD-banded launch permutation ----------
// conv1: OC=32, OH*OW=512*768, slab=256px, 1536 slabs/batch, 48 slabs/16-row band,
//        32 bands: x=blk&7 picks XCD, 4 bands per XCD per batch.
// conv2: OC=64, OH*OW=256*384, 384 slabs/batch, 24 slabs/16-row band, 16 bands:
//        2 bands per XCD per batch.
// BANDS template param: bands per XCD per batch (4 for conv1, 2 for conv2).
template<int STRIDE, int BANDS>
__global__ __launch_bounds__(256) void conv3x3_bn(
    const float* __restrict__ in, const float* __restrict__ wgt,
    const float* __restrict__ scl, const float* __restrict__ sft,
    float* __restrict__ out,
    int IC, int IH, int IW, int OC, int OH, int OW) {
  __shared__ float wl[1152];  // up to IC=128 * 9
  // --- launch-order permutation (bijection on 256-output chunks) ---
  int chw = (OH * OW) >> 8;            // slabs per (b,oc) plane
  int spb = chw / (8 * BANDS);         // slabs per band
  int x = blockIdx.x & 7;              // -> XCD (round-robin dispatch heuristic)
  int y = blockIdx.x >> 3;
  int per_b = OC * chw;                // chunks per batch
  int ypb = per_b >> 3;                // y-range per batch
  int bb = y / ypb;
  int rem = y % ypb;                   // [0, BANDS * spb * OC)
  int bandq = rem / (spb * OC);        // band index within this XCD
  int rem2 = rem % (spb * OC);
  int s_loc = rem2 / OC;
  int oc_r = rem2 % OC;
  int s = (x * BANDS + bandq) * spb + s_loc;   // global slab
  int chunk = bb * per_b + oc_r * chw + s;
  int idx = chunk * 256 + threadIdx.x;
  // --- body identical to R1 naive kernel from here on ---
  int ox = idx % OW;
  int tmp = idx / OW;
  int oy = tmp % OH;
  tmp /= OH;
  int oc = tmp % OC;
  int b = tmp / OC;
  int wn = IC * 9;
  for (int i = threadIdx.x; i < wn; i += 256) wl[i] = wgt[oc * wn + i];
  __syncthreads();

  const float* ip0 = in + (b * IC) * IH * IW;
  int iy0 = oy * STRIDE - 1;
  int ix0 = ox * STRIDE - 1;
  int plane = IH * IW;
  float acc = 0.f;
  if (iy0 >= 0 && iy0 + 2 < IH && ix0 >= 0 && ix0 + 2 < IW) {
    const float* ip = ip0 + iy0 * IW + ix0;
    const float* wp = wl;
    for (int ic = 0; ic < IC; ++ic) {
#pragma unroll
      for (int ky = 0; ky < 3; ++ky) {
        const float* r = ip + ky * IW;
        acc += r[0] * wp[ky * 3 + 0];
        acc += r[1] * wp[ky * 3 + 1];
        acc += r[2] * wp[ky * 3 + 2];
      }
      ip += plane;
      wp += 9;
    }
  } else {
    for (int ic = 0; ic < IC; ++ic) {
      const float* ip = ip0 + ic * plane;
      const float* wp = wl + ic * 9;
#pragma unroll
      for (int ky = 0; ky < 3; ++ky) {
        int iy = iy0 + ky;
        if (iy < 0 || iy >= IH) continue;
#pragma unroll
        for (int kx = 0; kx < 3; ++kx) {
          int ix = ix0 + kx;
          if (ix < 0 || ix >= IW) continue;
          acc += ip[iy * IW + ix] * wp[ky * 3 + kx];
        }
      }
    }
  }
  float r = acc * scl[oc] + sft[oc];
  out[idx] = r > 0.f ? r : 0.f;
}

// ---------- tiled conv (conv3, conv4, fw1 — R5/R6-verified) ----------
template<int STRIDE, int IC, int OCB, int OCT, int NOC4, int TY, int TX>
__global__ __launch_bounds__(256) void conv3x3_t(
    const float* __restrict__ in, const float* __restrict__ wgt,
    const float* __restrict__ scl, const float* __restrict__ sft,
    float* __restrict__ out, int IH, int IW, int OH, int OW) {
  constexpr int OCG = NOC4 * 4;
  constexpr int NOCG = OCB / OCG;
  constexpr int NPIX_T = 256 / NOCG;
  constexpr int PIX = (TY * TX) / NPIX_T;
  constexpr int PH = (TY - 1) * STRIDE + 3;
  constexpr int PW = (TX - 1) * STRIDE + 3;
  __shared__ float patch[PH * PW];
  __shared__ float wl[9 * OCB];

  int NTY = OH / TY, NTX = OW / TX;
  int ntiles = 4 * NTY * NTX;
  int ocs = blockIdx.x / ntiles;
  int r = blockIdx.x % ntiles;
  int b = r / (NTY * NTX);
  int t = r % (NTY * NTX);
  int tyi = t / NTX, txi = t % NTX;
  int oc_base = ocs * OCB;

  int tid = threadIdx.x;
  int pid = tid % NPIX_T;
  int ocg = tid / NPIX_T;

  int off[PIX], pyv[PIX], pxv[PIX];
#pragma unroll
  for (int i = 0; i < PIX; ++i) {
    int p = i * NPIX_T + pid;
    pyv[i] = p / TX;
    pxv[i] = p % TX;
    off[i] = (pyv[i] * STRIDE) * PW + pxv[i] * STRIDE;
  }

  float4 acc[PIX][NOC4];
#pragma unroll
  for (int i = 0; i < PIX; ++i)
#pragma unroll
    for (int j = 0; j < NOC4; ++j) acc[i][j] = make_float4(0.f, 0.f, 0.f, 0.f);

  const size_t plane_in = (size_t)IH * IW;
  const float* ibase = in + (size_t)b * IC * plane_in;
  int iy0 = tyi * TY * STRIDE - 1;
  int ix0 = txi * TX * STRIDE - 1;

#pragma unroll 1
  for (int ic = 0; ic < IC; ++ic) {
    const float* ip = ibase + (size_t)ic * plane_in;
    for (int i = tid; i < PH * PW; i += 256) {
      int py = i / PW, px = i % PW;
      int iy = iy0 + py, ix = ix0 + px;
      float v = 0.f;
      if (iy >= 0 && iy < IH && ix >= 0 && ix < IW) v = ip[(size_t)iy * IW + ix];
      patch[i] = v;
    }
    for (int i = tid; i < 9 * OCB; i += 256) {
      int oc = i / 9, k = i % 9;
      wl[k * OCB + oc] = wgt[((size_t)(oc_base + oc) * IC + ic) * 9 + k];
    }
    __syncthreads();

    const float4* wl4 = (const float4*)wl;
#pragma unroll
    for (int ky = 0; ky < 3; ++ky) {
#pragma unroll
      for (int kx = 0; kx < 3; ++kx) {
        float pv[PIX];
#pragma unroll
        for (int i = 0; i < PIX; ++i) pv[i] = patch[off[i] + ky * PW + kx];
        const float4* wr = wl4 + (ky * 3 + kx) * (OCB / 4) + ocg * NOC4;
#pragma unroll
        for (int j = 0; j < NOC4; ++j) {
          float4 w = wr[j];
#pragma unroll
          for (int i = 0; i < PIX; ++i) {
            acc[i][j].x = __builtin_fmaf(pv[i], w.x, acc[i][j].x);
            acc[i][j].y = __builtin_fmaf(pv[i], w.y, acc[i][j].y);
            acc[i][j].z = __builtin_fmaf(pv[i], w.z, acc[i][j].z);
            acc[i][j].w = __builtin_fmaf(pv[i], w.w, acc[i][j].w);
          }
        }
      }
    }
    __syncthreads();
  }

  int plane = OH * OW;
#pragma unroll
  for (int i = 0; i < PIX; ++i) {
    int oy = tyi * TY + pyv[i];
    int ox = txi * TX + pxv[i];
#pragma unroll
    for (int j = 0; j < NOC4; ++j) {
      int oc0 = oc_base + ocg * OCG + j * 4;
      float4 v = acc[i][j];
      float4 sc = ((const float4*)scl)[oc0 >> 2];
      float4 sh = ((const float4*)sft)[oc0 >> 2];
      float rx = __builtin_fmaf(v.x, sc.x, sh.x);
      float ry = __builtin_fmaf(v.y, sc.y, sh.y);
      float rz = __builtin_fmaf(v.z, sc.z, sh.z);
      float rw = __builtin_fmaf(v.w, sc.w, sh.w);
      rx = rx > 0.f ? rx : 0.f;
      ry = ry > 0.f ? ry : 0.f;
      rz = rz > 0.f ? rz : 0.f;
      rw = rw > 0.f ? rw : 0.f;
      size_t base = ((size_t)b * OCT + oc0) * plane + oy * OW + ox;
      out[base] = rx;
      out[base + plane] = ry;
      out[base + 2 * (size_t)plane] = rz;
      out[base + 3 * (size_t)plane] = rw;
    }
  }
}

// 1x1 conv 128->64 + bias, output (B, Hf, Wf, C). (R1-verbatim)
__global__ __launch_bounds__(256) void feat_head(
    const float* __restrict__ fh, const float* __restrict__ fw2,
    const float* __restrict__ fb, float* __restrict__ feats) {
  __shared__ float wl[128 * 64];
  for (int i = threadIdx.x; i < 8192; i += 256) {
    int c = i & 63, ic = i >> 6;
    wl[i] = fw2[c * 128 + ic];
  }
  __syncthreads();
  int t = blockIdx.x * 256 + threadIdx.x;
  int c = t & 63;
  int p = t >> 6;
  int b = p / 6144;
  int rem = p % 6144;
  const float* fp = fh + (b * 128) * 6144 + rem;
  float acc = fb[c];
#pragma unroll 4
  for (int ic = 0; ic < 128; ++ic) acc += fp[ic * 6144] * wl[(ic << 6) + c];
  feats[t] = acc;
}

// depth/opacity heads + backprojection + voxelization. (R1-verbatim)
__global__ __launch_bounds__(256) void depth_head(
    const float* __restrict__ x4, const float* __restrict__ dw,
    const float* __restrict__ dbias, const float* __restrict__ oww,
    const float* __restrict__ obias, const float* __restrict__ camK,
    const float* __restrict__ Tlc,
    int* __restrict__ xio, int* __restrict__ yio, float* __restrict__ bwo) {
  __shared__ float dwl[16 * 128];
  __shared__ float owl[128];
  for (int i = threadIdx.x; i < 2048; i += 256) dwl[i] = dw[i];
  if (threadIdx.x < 128) owl[threadIdx.x] = oww[threadIdx.x];
  __syncthreads();
  int p = blockIdx.x * 256 + threadIdx.x;
  int b = p / 6144;
  int rem = p % 6144;
  int y = rem / 96;
  int x = rem % 96;

  float lg[16];
#pragma unroll
  for (int j = 0; j < 16; ++j) lg[j] = dbias[j];
  float oa = obias[0];
  const float* fp = x4 + (b * 128) * 6144 + rem;
  for (int ic = 0; ic < 128; ++ic) {
    float f = fp[ic * 6144];
#pragma unroll
    for (int j = 0; j < 16; ++j) lg[j] += f * dwl[j * 128 + ic];
    oa += f * owl[ic];
  }
  float m = lg[0];
#pragma unroll
  for (int j = 1; j < 16; ++j) m = fmaxf(m, lg[j]);
  float se = 0.f, sz = 0.f;
#pragma unroll
  for (int j = 0; j < 16; ++j) {
    float e = expf(lg[j] - m);
    se += e;
    sz += e * (1.0f + (float)j * (59.0f / 15.0f));
  }
  float z = sz / se;
  float op = 1.f / (1.f + expf(-oa));

  const float* K = camK + b * 9;
  float fx = fmaxf(K[0], 1e-6f), fy = fmaxf(K[4], 1e-6f);
  float cx = K[2], cy = K[5];
  float xs = ((float)x + 0.5f) * 16.0f;
  float ys = ((float)y + 0.5f) * 16.0f;
  float xc = (xs - cx) * z / fx;
  float yc = (ys - cy) * z / fy;
  const float* T = Tlc + b * 16;
  float xw = T[0] * xc + T[1] * yc + T[2] * z + T[3];
  float yw = T[4] * xc + T[5] * yc + T[6] * z + T[7];
  float zw = T[8] * xc + T[9] * yc + T[10] * z + T[11];
  float xif = floorf((xw - (-51.2f)) / 0.4f);
  float yif = floorf((yw - (-51.2f)) / 0.4f);
  int xi = (int)xif, yi = (int)yif;
  bool inb = xi >= 0 && xi < 256 && yi >= 0 && yi < 256 && zw >= -5.0f && zw < 3.0f;
  float bw = (op >= 0.05f && inb) ? op : 0.f;
  xio[p] = xi;
  yio[p] = yi;
  bwo[p] = bw;
}

__global__ __launch_bounds__(256) void zerof4(float4* __restrict__ p) {
  int i = blockIdx.x * 256 + threadIdx.x;
  p[i] = make_float4(0.f, 0.f, 0.f, 0.f);
}

// 9-tap Gaussian scatter. (R1-verbatim)
__global__ __launch_bounds__(256) void splat(
    const float* __restrict__ feats, const int* __restrict__ xi,
    const int* __restrict__ yi, const float* __restrict__ bw,
    float* __restrict__ canvas, float* __restrict__ wacc) {
  int t = blockIdx.x * 256 + threadIdx.x;
  int c = t & 63;
  int p = t >> 6;
  float w0 = bw[p];
  if (w0 == 0.f) return;
  int X = xi[p], Y = yi[p];
  int b = p / 6144;
  float fv = feats[t];
  float* cb = canvas + ((size_t)b << 22);
  float* wb = wacc + (b << 16);
  const float kwt[3] = {1.0f, 0.45783335f, 0.20961137f};
#pragma unroll
  for (int dy = -1; dy <= 1; ++dy) {
    int ty = Y + dy;
    if (ty < 0 || ty > 255) continue;
#pragma unroll
    for (int dx = -1; dx <= 1; ++dx) {
      int tx = X + dx;
      if (tx < 0 || tx > 255) continue;
      float kw = kwt[dx * dx + dy * dy];
      atomicAdd(&cb[(((ty << 8) + tx) << 6) + c], fv * w0 * kw);
      if (c == 0) atomicAdd(&wb[(ty << 8) + tx], w0 * kw);
    }
  }
}

// normalize + NHWC->NCHW transpose. (R1-verbatim)
__global__ __launch_bounds__(256) void normalize_out(
    const float* __restrict__ canvas, const float* __restrict__ wacc,
    float* __restrict__ out) {
  __shared__ float tile[64][65];
  int blk = blockIdx.x;
  int b = blk >> 10;
  int s0 = (blk & 1023) << 6;
  int tid = threadIdx.x;
  const float* cb = canvas + ((size_t)b << 22);
  const float* wb = wacc + (b << 16);
#pragma unroll
  for (int it = 0; it < 16; ++it) {
    int l = it * 256 + tid;
    int pix = l >> 6, ch = l & 63;
    float w = wb[s0 + pix];
    float n = w > 0.f ? 1.f / fmaxf(w, 1e-6f) : 0.f;
    tile[pix][ch] = cb[(size_t)(s0 + pix) * 64 + ch] * n;
  }
  __syncthreads();
  float* ob = out + ((size_t)b << 22);
#pragma unroll
  for (int it = 0; it < 16; ++it) {
    int l = it * 256 + tid;
    int ch = l >> 6, pix = l & 63;
    ob[(size_t)ch * 65536 + s0 + pix] = tile[pix][ch];
  }
}

extern "C" void kernel_launch(void* const* d_in, const int* in_sizes, int n_in,
                              void* d_out, int out_size, void* d_ws, size_t ws_size,
                              hipStream_t stream) {
  const float* images = (const float*)d_in[0];
  const float* camK   = (const float*)d_in[1];
  const float* Tlc    = (const float*)d_in[2];
  const float* w1 = (const float*)d_in[3];
  const float* s1 = (const float*)d_in[4];
  const float* b1 = (const float*)d_in[5];
  const float* w2 = (const float*)d_in[6];
  const float* s2 = (const float*)d_in[7];
  const float* b2 = (const float*)d_in[8];
  const float* w3 = (const float*)d_in[9];
  const float* s3 = (const float*)d_in[10];
  const float* b3 = (const float*)d_in[11];
  const float* w4 = (const float*)d_in[12];
  const float* s4 = (const float*)d_in[13];
  const float* b4 = (const float*)d_in[14];
  const float* fw1 = (const float*)d_in[15];
  const float* fs1 = (const float*)d_in[16];
  const float* fb1 = (const float*)d_in[17];
  const float* fw2 = (const float*)d_in[18];
  const float* fbias2 = (const float*)d_in[19];
  const float* dw = (const float*)d_in[20];
  const float* dbias = (const float*)d_in[21];
  const float* ow = (const float*)d_in[22];
  const float* obias = (const float*)d_in[23];
  float* out = (float*)d_out;

  // workspace layout (floats), aliased (same as R1/R5/R6):
  //   A [50,331,648]: conv1 out -> conv3 out (12.58M) -> canvas(16.78M)+wacc(0.26M)
  //   B [25,165,824]: conv2 out -> c4(3.15M) | fh(3.15M) | feats(1.57M) | xi/yi/bw
  float* ws = (float*)d_ws;
  float* A = ws;
  float* Bb = ws + 50331648;
  float* c4   = Bb;
  float* fhb  = Bb + 3145728;
  float* ftb  = Bb + 6291456;
  int*   xib  = (int*)(Bb + 7864320);
  int*   yib  = xib + 24576;
  float* bwb  = (float*)(yib + 24576);
  float* canvas = A;
  float* waccb  = A + 16777216;

  // conv1: 1536 slabs/batch, 32 bands of 48 slabs -> BANDS=4 per XCD per batch
  conv3x3_bn<2, 4><<<196608, 256, 0, stream>>>(images, w1, s1, b1, A, 3, 1024, 1536, 32, 512, 768);
  // conv2: 384 slabs/batch, 16 bands of 24 slabs -> BANDS=2 per XCD per batch
  conv3x3_bn<2, 2><<<98304, 256, 0, stream>>>(A, w2, s2, b2, Bb, 32, 512, 768, 64, 256, 384);
  // conv3, conv4, fw1: tiled (verified)
  conv3x3_t<2, 64, 64, 128, 8, 8, 32><<<768, 256, 0, stream>>>(
      Bb, w3, s3, b3, A, 256, 384, 128, 192);
  conv3x3_t<2, 128, 32, 128, 4, 8, 16><<<768, 256, 0, stream>>>(
      A, w4, s4, b4, c4, 128, 192, 64, 96);
  conv3x3_t<1, 128, 32, 128, 4, 8, 16><<<768, 256, 0, stream>>>(
      c4, fw1, fs1, fb1, fhb, 64, 96, 64, 96);
  feat_head<<<6144, 256, 0, stream>>>(fhb, fw2, fbias2, ftb);
  depth_head<<<96, 256, 0, stream>>>(c4, dw, dbias, ow, obias, camK, Tlc, xib, yib, bwb);
  zerof4<<<16640, 256, 0, stream>>>((float4*)canvas);
  splat<<<6144, 256, 0, stream>>>(ftb, xib, yib, bwb, canvas, waccb);
  normalize_out<<<4096, 256, 0, stream>>>(canvas, waccb, out);
}